// Round 5
// baseline (1005.665 us; speedup 1.0000x reference)
//
#include <hip/hip_runtime.h>
#include <hip/hip_bf16.h>

// B=32, N=4096, P=256, L=16, DR=128, H=128, NUM_REL=400.
// Contract (derived r0-r4): float inputs f32, ints int32, OUTPUT f32 [32][128].
// Detectors retained as insurance: float dtype (f32/bf16), int width (i32/i64).
// Pipeline: W_cat+bias prep, rel_proj precompute (kills rel half of x@W_ih.T),
// length-sorted path batching (blocks run ~len steps), register-tiled fp32
// LSTM GEMM, collapsed attention epilogue. All scratch in __device__ globals.

#define B_   32
#define N_   4096
#define P_   256
#define L_   16
#define DR_  128
#define H_   128
#define G4_  512          // 4*H
#define K_   256          // H + DR  (A = [h | x_node])
#define NPATH (B_*P_)     // 8192
#define NPB  16           // paths per LSTM block

typedef unsigned short bfraw;

__device__ int   g_isbf16;
__device__ int   g_isi64;
__device__ float g_Wcat[G4_ * K_];        // [512][256]
__device__ float g_relproj[400 * G4_];    // [400][512]
__device__ float g_bias[G4_];
__device__ int   g_perm[NPATH];
__device__ float g_last[NPATH * H_];      // f32 [8192][128]

__device__ __forceinline__ float bfc(bfraw v) {
    return __uint_as_float(((unsigned)v) << 16);
}
__device__ __forceinline__ float ld(const void* p, size_t i, int isbf) {
    return isbf ? bfc(((const bfraw*)p)[i]) : ((const float*)p)[i];
}
__device__ __forceinline__ float sigf(float x) { return 1.0f / (1.0f + __expf(-x)); }
__device__ __forceinline__ float tanhfast(float x) { return 2.0f * sigf(2.0f * x) - 1.0f; }

// ---------------------------------------------------------------------------
// Detect float dtype (node_opt) and integer width (node_idx).
__global__ __launch_bounds__(256) void k_detect(const void* __restrict__ node_opt,
                                                const int*  __restrict__ node_idx)
{
    __shared__ int s_big, s_nz;
    const int tid = threadIdx.x;
    if (tid == 0) { s_big = 0; s_nz = 0; }
    __syncthreads();
    const unsigned short* u = (const unsigned short*)node_opt;
    int big = 0;
    for (int i = tid; i < 2048; i += 256) {
        const float v = fabsf(bfc(u[i]));
        big |= !(v < 1.0e3f);                 // NaN-safe
    }
    if (big) s_big = 1;
    int nz = 0;
    for (int i = tid; i < 512; i += 256) nz |= (node_idx[2 * i + 1] != 0);
    if (nz) s_nz = 1;
    __syncthreads();
    if (tid == 0) { g_isbf16 = s_big ? 0 : 1; g_isi64 = s_nz ? 0 : 1; }
}

// ---------------------------------------------------------------------------
// W_cat[j][k] = (k<128 ? W_hh[j][k] : W_ih[j][k-128]); bias = b_ih + b_hh
__global__ __launch_bounds__(256) void k_prep(
    const void* __restrict__ W_ih, const void* __restrict__ W_hh,
    const void* __restrict__ b_ih, const void* __restrict__ b_hh)
{
    const int isbf = g_isbf16;
    const int j = blockIdx.x;          // 0..511
    const int k = threadIdx.x;         // 0..255
    g_Wcat[j * K_ + k] = (k < H_) ? ld(W_hh, (size_t)j * H_ + k, isbf)
                                  : ld(W_ih, (size_t)j * 256 + (k - H_), isbf);
    if (k == 0) g_bias[j] = ld(b_ih, j, isbf) + ld(b_hh, j, isbf);
}

// rel_proj[r][j] = sum_d rel_embeds[r][d] * W_ih[j][128+d]
__global__ __launch_bounds__(256) void k_relproj(
    const void* __restrict__ rel_embeds, const void* __restrict__ W_ih)
{
    __shared__ float relv[DR_];
    const int isbf = g_isbf16;
    const int r = blockIdx.x;          // 0..399
    const int tid = threadIdx.x;
    if (tid < DR_) relv[tid] = ld(rel_embeds, (size_t)r * DR_ + tid, isbf);
    __syncthreads();
    float s0 = 0.f, s1 = 0.f;
    for (int d = 0; d < DR_; ++d) {
        const float rv = relv[d];
        s0 = fmaf(rv, ld(W_ih, (size_t)tid * 256 + DR_ + d, isbf), s0);
        s1 = fmaf(rv, ld(W_ih, (size_t)(tid + 256) * 256 + DR_ + d, isbf), s1);
    }
    g_relproj[r * G4_ + tid]       = s0;
    g_relproj[r * G4_ + 256 + tid] = s1;
}

// ---------------------------------------------------------------------------
// Single-block counting sort by length (descending: len=16 bucket first).
__global__ __launch_bounds__(256) void k_sort(const int* __restrict__ path_lens)
{
    __shared__ int hist[16], cur[16];
    const int i64 = g_isi64;
    const int tid = threadIdx.x;
    if (tid < 16) hist[tid] = 0;
    __syncthreads();
    for (int p = tid; p < NPATH; p += 256) {
        const int len = i64 ? path_lens[2 * p] : path_lens[p];
        atomicAdd(&hist[len - 1], 1);
    }
    __syncthreads();
    if (tid == 0) {
        int off = 0;
        for (int b = 15; b >= 0; --b) { cur[b] = off; off += hist[b]; }
    }
    __syncthreads();
    for (int p = tid; p < NPATH; p += 256) {
        const int len = i64 ? path_lens[2 * p] : path_lens[p];
        const int pos = atomicAdd(&cur[len - 1], 1);
        g_perm[pos] = p;
    }
}

// ---------------------------------------------------------------------------
// Main LSTM kernel. 512 blocks x 256 threads, NPB=16 paths/block.
// Per-thread tile: 4 gates x 4 units x 2 paths.  tid = ug*8 + pg.
__global__ __launch_bounds__(256) void k_lstm(
    const void* __restrict__ graph_embed,    // [32][4096][128] f32 (or bf16)
    const int*  __restrict__ node_idx,       // [8192][16]
    const int*  __restrict__ rel_idx,        // [8192][16]
    const int*  __restrict__ path_lens)      // [8192]
{
    __shared__ float A[NPB][K_ + 4];         // stride 260 floats
    __shared__ int s_pid[NPB], s_len[NPB];
    __shared__ int s_nid[NPB][L_], s_rid[NPB][L_];

    const int isbf = g_isbf16;
    const int i64  = g_isi64;
    const int tid  = threadIdx.x;
    if (tid < NPB) {
        const int pid = g_perm[blockIdx.x * NPB + tid];
        s_pid[tid] = pid;
        s_len[tid] = i64 ? path_lens[2 * pid] : path_lens[pid];
    }
    __syncthreads();
    {   // 256 threads = 16 paths x 16 steps
        const int m = tid >> 4, t = tid & 15;
        const int idx = s_pid[m] * L_ + t;
        s_nid[m][t] = i64 ? node_idx[2 * idx] : node_idx[idx];
        s_rid[m][t] = i64 ? rel_idx[2 * idx]  : rel_idx[idx];
    }
    {   // zero h region
        const int m = tid >> 4, c0 = (tid & 15) * 8;
        #pragma unroll
        for (int i = 0; i < 8; ++i) A[m][c0 + i] = 0.f;
    }
    __syncthreads();

    int maxlen = 0;
    #pragma unroll
    for (int m = 0; m < NPB; ++m) maxlen = max(maxlen, s_len[m]);

    const int ug = tid >> 3;        // 0..31 -> units u0..u0+3
    const int pg = tid & 7;         // 0..7  -> paths m0, m0+1
    const int u0 = ug << 2;
    const int m0 = pg << 1;

    float4 breg[4];
    #pragma unroll
    for (int g = 0; g < 4; ++g) breg[g] = *(const float4*)(g_bias + (g << 7) + u0);

    float c[4][2];
    #pragma unroll
    for (int du = 0; du < 4; ++du) { c[du][0] = 0.f; c[du][1] = 0.f; }

    for (int t = 0; t < maxlen; ++t) {
        // ---- gather x_node into A[:,128:256] (zeros when t >= len) ----
        {
            const int m = tid >> 4, lane = tid & 15;
            float4 f0 = make_float4(0.f, 0.f, 0.f, 0.f);
            float4 f1 = make_float4(0.f, 0.f, 0.f, 0.f);
            if (t < s_len[m]) {
                const size_t off = (size_t)(s_pid[m] >> 8) * (N_ * DR_)
                                 + (size_t)s_nid[m][t] * DR_ + lane * 8;
                if (isbf) {
                    const uint4 raw = *(const uint4*)((const bfraw*)graph_embed + off);
                    f0.x = __uint_as_float(raw.x << 16); f0.y = __uint_as_float(raw.x & 0xFFFF0000u);
                    f0.z = __uint_as_float(raw.y << 16); f0.w = __uint_as_float(raw.y & 0xFFFF0000u);
                    f1.x = __uint_as_float(raw.z << 16); f1.y = __uint_as_float(raw.z & 0xFFFF0000u);
                    f1.z = __uint_as_float(raw.w << 16); f1.w = __uint_as_float(raw.w & 0xFFFF0000u);
                } else {
                    const float* gf = (const float*)graph_embed + off;
                    f0 = *(const float4*)gf;
                    f1 = *(const float4*)(gf + 4);
                }
            }
            *(float4*)&A[m][H_ + lane * 8]     = f0;
            *(float4*)&A[m][H_ + lane * 8 + 4] = f1;
        }
        __syncthreads();

        // ---- accumulators: bias + (t < len-1 ? rel_proj[rid] : 0) ----
        float acc[4][4][2];
        #pragma unroll
        for (int dm = 0; dm < 2; ++dm) {
            const int m = m0 + dm;
            const float relm = (t < s_len[m] - 1) ? 1.0f : 0.0f;
            const float* rp = g_relproj + (size_t)s_rid[m][t] * G4_ + u0;
            #pragma unroll
            for (int g = 0; g < 4; ++g) {
                const float4 r4 = *(const float4*)(rp + (g << 7));
                acc[g][0][dm] = breg[g].x + relm * r4.x;
                acc[g][1][dm] = breg[g].y + relm * r4.y;
                acc[g][2][dm] = breg[g].z + relm * r4.z;
                acc[g][3][dm] = breg[g].w + relm * r4.w;
            }
        }

        // ---- GEMM: acc[g][du][dm] += sum_k W_cat[g*128+u0+du][k] * A[m0+dm][k] ----
        for (int k4 = 0; k4 < K_ / 4; ++k4) {
            const float4 a0 = *(const float4*)&A[m0][k4 << 2];
            const float4 a1 = *(const float4*)&A[m0 + 1][k4 << 2];
            #pragma unroll
            for (int g = 0; g < 4; ++g) {
                #pragma unroll
                for (int du = 0; du < 4; ++du) {
                    const float4 w = *(const float4*)(g_Wcat + (size_t)((g << 7) + u0 + du) * K_ + (k4 << 2));
                    acc[g][du][0] = fmaf(w.x, a0.x, fmaf(w.y, a0.y, fmaf(w.z, a0.z, fmaf(w.w, a0.w, acc[g][du][0]))));
                    acc[g][du][1] = fmaf(w.x, a1.x, fmaf(w.y, a1.y, fmaf(w.z, a1.z, fmaf(w.w, a1.w, acc[g][du][1]))));
                }
            }
        }
        __syncthreads();   // all A reads done before h overwrite

        // ---- gates, state update, h write, snapshot at t == len-1 ----
        #pragma unroll
        for (int dm = 0; dm < 2; ++dm) {
            const int m = m0 + dm;
            float hh[4];
            #pragma unroll
            for (int du = 0; du < 4; ++du) {
                const float ig = sigf(acc[0][du][dm]);
                const float fg = sigf(acc[1][du][dm]);
                const float gg = tanhfast(acc[2][du][dm]);
                const float og = sigf(acc[3][du][dm]);
                const float cc = fg * c[du][dm] + ig * gg;
                c[du][dm] = cc;
                hh[du] = og * tanhfast(cc);
            }
            const float4 hv = make_float4(hh[0], hh[1], hh[2], hh[3]);
            *(float4*)&A[m][u0] = hv;
            if (t == s_len[m] - 1)
                *(float4*)(g_last + (size_t)s_pid[m] * H_ + u0) = hv;
        }
        __syncthreads();
    }
}

// ---------------------------------------------------------------------------
// Attention epilogue, one block per batch element.
// logit_p = scale*((Wk^T q)·last_p + q·bk); ctx = Wv (sum_p attn_p last_p) + bv
__global__ __launch_bounds__(256) void k_attn(
    const void* __restrict__ node_opt,    // [32][128]
    const void* __restrict__ in_proj_w,   // [384][128]
    const void* __restrict__ in_proj_b,   // [384]
    const void* __restrict__ out_proj_w,  // [128][128]
    const void* __restrict__ out_proj_b,  // [128]
    float* __restrict__ out)              // [32][128] f32
{
    const int isbf = g_isbf16;
    const int b = blockIdx.x, tid = threadIdx.x;
    __shared__ float q[128], qk[128], sv2[2][128], ctx[128];
    __shared__ float logits[256];
    __shared__ float red[12];

    if (tid < 128) {
        float s = 0.f;
        for (int j = 0; j < 128; ++j)
            s = fmaf(ld(node_opt, b * 128 + j, isbf), ld(in_proj_w, (size_t)tid * 128 + j, isbf), s);
        q[tid] = s + ld(in_proj_b, tid, isbf);
    }
    __syncthreads();
    if (tid < 128) {
        float s = 0.f;
        for (int j = 0; j < 128; ++j)
            s = fmaf(q[j], ld(in_proj_w, (size_t)(128 + j) * 128 + tid, isbf), s);
        qk[tid] = s;
    } else if (tid == 128) {
        float s = 0.f;
        for (int j = 0; j < 128; ++j)
            s = fmaf(q[j], ld(in_proj_b, 128 + j, isbf), s);
        red[10] = s;   // q . bk
    }
    __syncthreads();
    {   // logit for path p = tid
        float s = 0.f;
        const float* lp = g_last + ((size_t)b * 256 + tid) * H_;
        for (int u = 0; u < 128; ++u)
            s = fmaf(qk[u], lp[u], s);
        logits[tid] = (s + red[10]) * 0.08838834764831845f;  // 1/sqrt(128)
    }
    __syncthreads();
    // softmax over 256
    float v = logits[tid];
    #pragma unroll
    for (int off = 32; off > 0; off >>= 1) v = fmaxf(v, __shfl_xor(v, off, 64));
    if ((tid & 63) == 0) red[tid >> 6] = v;
    __syncthreads();
    if (tid == 0) red[8] = fmaxf(fmaxf(red[0], red[1]), fmaxf(red[2], red[3]));
    __syncthreads();
    const float e = __expf(logits[tid] - red[8]);
    float sum = e;
    #pragma unroll
    for (int off = 32; off > 0; off >>= 1) sum += __shfl_xor(sum, off, 64);
    if ((tid & 63) == 0) red[4 + (tid >> 6)] = sum;
    __syncthreads();
    if (tid == 0) red[9] = red[4] + red[5] + red[6] + red[7];
    __syncthreads();
    logits[tid] = e / red[9];
    __syncthreads();
    {   // sv[u] = sum_p attn[p] * last[b,p,u]
        const int u = tid & 127, half = tid >> 7;
        float s = 0.f;
        const float* lb = g_last + ((size_t)b * 256 + half * 128) * H_ + u;
        for (int p = 0; p < 128; ++p)
            s = fmaf(logits[half * 128 + p], lb[(size_t)p * H_], s);
        sv2[half][u] = s;
    }
    __syncthreads();
    if (tid < 128) q[tid] = sv2[0][tid] + sv2[1][tid];   // reuse q[] as sv
    __syncthreads();
    if (tid < 128) {
        float s = 0.f;
        for (int u = 0; u < 128; ++u)
            s = fmaf(ld(in_proj_w, (size_t)(256 + tid) * 128 + u, isbf), q[u], s);
        ctx[tid] = s + ld(in_proj_b, 256 + tid, isbf);
    }
    __syncthreads();
    if (tid < 128) {
        float s = 0.f;
        for (int d = 0; d < 128; ++d)
            s = fmaf(ld(out_proj_w, (size_t)tid * 128 + d, isbf), ctx[d], s);
        out[b * 128 + tid] = s + ld(out_proj_b, tid, isbf);   // f32 store
    }
}

// ---------------------------------------------------------------------------
extern "C" void kernel_launch(void* const* d_in, const int* in_sizes, int n_in,
                              void* d_out, int out_size, void* d_ws, size_t ws_size,
                              hipStream_t stream)
{
    const void* graph_embed = d_in[0];
    const void* node_opt    = d_in[1];
    const void* rel_embeds  = d_in[2];
    const void* W_ih        = d_in[3];
    const void* W_hh        = d_in[4];
    const void* b_ih        = d_in[5];
    const void* b_hh        = d_in[6];
    const void* in_proj_w   = d_in[7];
    const void* in_proj_b   = d_in[8];
    const void* out_proj_w  = d_in[9];
    const void* out_proj_b  = d_in[10];
    const int* node_idx  = (const int*)d_in[11];
    const int* rel_idx   = (const int*)d_in[12];
    const int* path_lens = (const int*)d_in[13];
    (void)d_ws; (void)ws_size; (void)in_sizes; (void)n_in; (void)out_size;

    hipLaunchKernelGGL(k_detect, dim3(1), dim3(256), 0, stream, node_opt, node_idx);
    hipLaunchKernelGGL(k_prep, dim3(512), dim3(256), 0, stream, W_ih, W_hh, b_ih, b_hh);
    hipLaunchKernelGGL(k_relproj, dim3(400), dim3(256), 0, stream, rel_embeds, W_ih);
    hipLaunchKernelGGL(k_sort, dim3(1), dim3(256), 0, stream, path_lens);
    hipLaunchKernelGGL(k_lstm, dim3(NPATH / NPB), dim3(256), 0, stream,
                       graph_embed, node_idx, rel_idx, path_lens);
    hipLaunchKernelGGL(k_attn, dim3(B_), dim3(256), 0, stream,
                       node_opt, in_proj_w, in_proj_b, out_proj_w, out_proj_b,
                       (float*)d_out);
}

// Round 6
// 482.692 us; speedup vs baseline: 2.0834x; 2.0834x over previous
//
#include <hip/hip_runtime.h>
#include <hip/hip_bf16.h>

// B=32, N=4096, P=256, L=16, DR=128, H=128, NUM_REL=400.
// Contract (verified r5): float inputs f32, ints int32, output f32 [32][128].
// r5 passed (absmax 3e-8) with fp32 VALU LSTM at 837us, MfmaUtil=0.
// This round: bf16 MFMA LSTM. K=384 = [h | node | rel] (rel folded into GEMM,
// rel_proj kernel deleted). fp32 cell state + fp32 accumulators; only GEMM
// operands are bf16. Layouts per HW-verified notes (m89/m120):
//   A[m=lane&15][k=quad*8+j], B[n=lane&15][k=quad*8+j], C col=lane&15,
//   row=quad*4+reg.

#define B_    32
#define N_    4096
#define L_    16
#define DR_   128
#define H_    128
#define G4_   512
#define KB_   384        // h(128) | node(128) | rel(128)
#define AST   392        // LDS A row stride in bf16 (784B, 16B-aligned, 2-way banks)
#define NPATH 8192
#define NPB   16

typedef unsigned short bfraw;
typedef short short8 __attribute__((ext_vector_type(8)));
typedef float f32x4 __attribute__((ext_vector_type(4)));

__device__ int   g_isbf16;
__device__ int   g_isi64;
__device__ __align__(16) bfraw g_Wbf[G4_ * KB_];   // [512][384] bf16, row-major
__device__ float g_bias[G4_];
__device__ int   g_perm[NPATH];
__device__ float g_last[NPATH * H_];               // f32 [8192][128]

__device__ __forceinline__ float bfc(bfraw v) {
    return __uint_as_float(((unsigned)v) << 16);
}
__device__ __forceinline__ bfraw f2b(float f) {    // RNE f32->bf16
    unsigned u = __float_as_uint(f);
    return (bfraw)((u + 0x7FFFu + ((u >> 16) & 1u)) >> 16);
}
__device__ __forceinline__ unsigned pk2(float a, float b) {
    return (unsigned)f2b(a) | ((unsigned)f2b(b) << 16);
}
__device__ __forceinline__ float ld(const void* p, size_t i, int isbf) {
    return isbf ? bfc(((const bfraw*)p)[i]) : ((const float*)p)[i];
}
__device__ __forceinline__ float sigf(float x) { return 1.0f / (1.0f + __expf(-x)); }
__device__ __forceinline__ float tanhfast(float x) { return 2.0f * sigf(2.0f * x) - 1.0f; }

// ---------------------------------------------------------------------------
__global__ __launch_bounds__(256) void k_detect(const void* __restrict__ node_opt,
                                                const int*  __restrict__ node_idx)
{
    __shared__ int s_big, s_nz;
    const int tid = threadIdx.x;
    if (tid == 0) { s_big = 0; s_nz = 0; }
    __syncthreads();
    const unsigned short* u = (const unsigned short*)node_opt;
    int big = 0;
    for (int i = tid; i < 2048; i += 256) {
        const float v = fabsf(bfc(u[i]));
        big |= !(v < 1.0e3f);                 // NaN-safe
    }
    if (big) s_big = 1;
    int nz = 0;
    for (int i = tid; i < 512; i += 256) nz |= (node_idx[2 * i + 1] != 0);
    if (nz) s_nz = 1;
    __syncthreads();
    if (tid == 0) { g_isbf16 = s_big ? 0 : 1; g_isi64 = s_nz ? 0 : 1; }
}

// ---------------------------------------------------------------------------
// g_Wbf[j][k] = bf16( k<128 ? W_hh[j][k] : W_ih[j][k-128] )  (k-128 covers
// node cols 0..127 then rel cols 128..255 of W_ih contiguously).
__global__ __launch_bounds__(384) void k_prep(
    const void* __restrict__ W_ih, const void* __restrict__ W_hh,
    const void* __restrict__ b_ih, const void* __restrict__ b_hh)
{
    const int isbf = g_isbf16;
    const int j = blockIdx.x;          // 0..511
    const int k = threadIdx.x;         // 0..383
    const float v = (k < H_) ? ld(W_hh, (size_t)j * H_ + k, isbf)
                             : ld(W_ih, (size_t)j * 256 + (k - H_), isbf);
    g_Wbf[j * KB_ + k] = f2b(v);
    if (k == 0) g_bias[j] = ld(b_ih, j, isbf) + ld(b_hh, j, isbf);
}

// ---------------------------------------------------------------------------
__global__ __launch_bounds__(256) void k_sort(const int* __restrict__ path_lens)
{
    __shared__ int hist[16], cur[16];
    const int i64 = g_isi64;
    const int tid = threadIdx.x;
    if (tid < 16) hist[tid] = 0;
    __syncthreads();
    for (int p = tid; p < NPATH; p += 256) {
        const int len = i64 ? path_lens[2 * p] : path_lens[p];
        atomicAdd(&hist[len - 1], 1);
    }
    __syncthreads();
    if (tid == 0) {
        int off = 0;
        for (int b = 15; b >= 0; --b) { cur[b] = off; off += hist[b]; }
    }
    __syncthreads();
    for (int p = tid; p < NPATH; p += 256) {
        const int len = i64 ? path_lens[2 * p] : path_lens[p];
        const int pos = atomicAdd(&cur[len - 1], 1);
        g_perm[pos] = p;
    }
}

// ---------------------------------------------------------------------------
// MFMA LSTM: 512 blocks x 256 threads, 16 paths/block (M=16), N=512, K=384.
// Wave w owns n-tiles {gate*8 + 2w + sub}: lane holds i,f,g,o for its
// (4 paths x 2 units) -> lane-local cell update, c in fp32 VGPRs.
__global__ __launch_bounds__(256) void k_lstm(
    const void* __restrict__ graph_embed,   // [32][4096][128] f32 (or bf16)
    const void* __restrict__ rel_embeds,    // [400][128]
    const int*  __restrict__ node_idx,      // [8192][16]
    const int*  __restrict__ rel_idx,       // [8192][16]
    const int*  __restrict__ path_lens)     // [8192]
{
    __shared__ __align__(16) bfraw A[NPB][AST];   // [path][ h | node | rel ]
    __shared__ int s_pid[NPB], s_len[NPB];
    __shared__ int s_nid[NPB][L_], s_rid[NPB][L_];

    const int isbf = g_isbf16;
    const int i64  = g_isi64;
    const int tid  = threadIdx.x;

    if (tid < NPB) {
        const int pid = g_perm[blockIdx.x * NPB + tid];
        s_pid[tid] = pid;
        s_len[tid] = i64 ? path_lens[2 * pid] : path_lens[pid];
    }
    __syncthreads();
    {   // indices: 16 paths x 16 steps
        const int m = tid >> 4, t = tid & 15;
        const int idx = s_pid[m] * L_ + t;
        s_nid[m][t] = i64 ? node_idx[2 * idx] : node_idx[idx];
        s_rid[m][t] = i64 ? rel_idx[2 * idx]  : rel_idx[idx];
    }
    {   // zero h region (k<128): 16*128 bf16, 8 per thread, 16B stores
        const int m = tid >> 4, i0 = (tid & 15) * 8;
        const uint4 z = make_uint4(0, 0, 0, 0);
        *(uint4*)&A[m][i0] = z;
    }
    __syncthreads();

    int maxlen = 0;
    #pragma unroll
    for (int m = 0; m < NPB; ++m) maxlen = max(maxlen, s_len[m]);

    const int w    = tid >> 6;     // wave 0..3
    const int l    = tid & 63;
    const int quad = l >> 4;
    const int col  = l & 15;

    // B row pointers + bias for the 8 owned n-tiles (j = gate*2 + sub)
    const bfraw* bp[8];
    float bq[8];
    #pragma unroll
    for (int j = 0; j < 8; ++j) {
        const int gate = j >> 1, sub = j & 1;
        const int n = gate * 128 + w * 32 + sub * 16 + col;
        bp[j] = g_Wbf + (size_t)n * KB_ + quad * 8;
        bq[j] = g_bias[n];
    }
    const bfraw* ab = &A[col][quad * 8];   // A-operand base (m = lane&15)

    float c[2][4];
    #pragma unroll
    for (int s = 0; s < 2; ++s)
        #pragma unroll
        for (int r = 0; r < 4; ++r) c[s][r] = 0.f;

    for (int t = 0; t < maxlen; ++t) {
        // ---- stage node (k 128..255) and rel (k 256..383) as bf16 ----
        {
            const int m = tid >> 4, i0 = (tid & 15) * 8;
            const int len = s_len[m];
            uint4 npk = make_uint4(0, 0, 0, 0);
            uint4 rpk = make_uint4(0, 0, 0, 0);
            if (t < len) {
                const size_t off = (size_t)(s_pid[m] >> 8) * (N_ * DR_)
                                 + (size_t)s_nid[m][t] * DR_ + i0;
                if (isbf) {
                    npk = *(const uint4*)((const bfraw*)graph_embed + off);
                } else {
                    const float* gp = (const float*)graph_embed + off;
                    const float4 a = *(const float4*)gp;
                    const float4 b = *(const float4*)(gp + 4);
                    npk = make_uint4(pk2(a.x, a.y), pk2(a.z, a.w),
                                     pk2(b.x, b.y), pk2(b.z, b.w));
                }
            }
            if (t < len - 1) {
                const size_t off = (size_t)s_rid[m][t] * DR_ + i0;
                if (isbf) {
                    rpk = *(const uint4*)((const bfraw*)rel_embeds + off);
                } else {
                    const float* rp = (const float*)rel_embeds + off;
                    const float4 a = *(const float4*)rp;
                    const float4 b = *(const float4*)(rp + 4);
                    rpk = make_uint4(pk2(a.x, a.y), pk2(a.z, a.w),
                                     pk2(b.x, b.y), pk2(b.z, b.w));
                }
            }
            *(uint4*)&A[m][128 + i0] = npk;
            *(uint4*)&A[m][256 + i0] = rpk;
        }
        __syncthreads();

        // ---- MFMA: D[m][n] += sum_k A[m][k] * W[n][k], K=384 ----
        f32x4 acc[8];
        #pragma unroll
        for (int j = 0; j < 8; ++j) {
            const float b = bq[j];
            acc[j][0] = b; acc[j][1] = b; acc[j][2] = b; acc[j][3] = b;
        }
        #pragma unroll
        for (int ks = 0; ks < KB_ / 32; ++ks) {
            const short8 a = *(const short8*)(ab + ks * 32);
            #pragma unroll
            for (int j = 0; j < 8; ++j) {
                const short8 b = *(const short8*)(bp[j] + ks * 32);
                acc[j] = __builtin_amdgcn_mfma_f32_16x16x32_bf16(a, b, acc[j], 0, 0, 0);
            }
        }
        __syncthreads();   // all A reads done before h overwrite

        // ---- lane-local gates + cell update + h write ----
        #pragma unroll
        for (int sub = 0; sub < 2; ++sub) {
            const int u = w * 32 + sub * 16 + col;
            #pragma unroll
            for (int r = 0; r < 4; ++r) {
                const int m = quad * 4 + r;
                const float ig = sigf(acc[0 + sub][r]);
                const float fg = sigf(acc[2 + sub][r]);
                const float gg = tanhfast(acc[4 + sub][r]);
                const float og = sigf(acc[6 + sub][r]);
                const float cc = fg * c[sub][r] + ig * gg;
                c[sub][r] = cc;
                const float h = og * tanhfast(cc);
                A[m][u] = f2b(h);
                if (t == s_len[m] - 1)
                    g_last[(size_t)s_pid[m] * H_ + u] = h;
            }
        }
        // epilogue writes (k<128) and next staging writes (k>=128) are
        // disjoint; barrier at top of next iteration orders h vs A-reads.
    }
}

// ---------------------------------------------------------------------------
// Attention epilogue, one block per batch element (unchanged from r5).
__global__ __launch_bounds__(256) void k_attn(
    const void* __restrict__ node_opt,    // [32][128]
    const void* __restrict__ in_proj_w,   // [384][128]
    const void* __restrict__ in_proj_b,   // [384]
    const void* __restrict__ out_proj_w,  // [128][128]
    const void* __restrict__ out_proj_b,  // [128]
    float* __restrict__ out)              // [32][128] f32
{
    const int isbf = g_isbf16;
    const int b = blockIdx.x, tid = threadIdx.x;
    __shared__ float q[128], qk[128], sv2[2][128], ctx[128];
    __shared__ float logits[256];
    __shared__ float red[12];

    if (tid < 128) {
        float s = 0.f;
        for (int j = 0; j < 128; ++j)
            s = fmaf(ld(node_opt, b * 128 + j, isbf), ld(in_proj_w, (size_t)tid * 128 + j, isbf), s);
        q[tid] = s + ld(in_proj_b, tid, isbf);
    }
    __syncthreads();
    if (tid < 128) {
        float s = 0.f;
        for (int j = 0; j < 128; ++j)
            s = fmaf(q[j], ld(in_proj_w, (size_t)(128 + j) * 128 + tid, isbf), s);
        qk[tid] = s;
    } else if (tid == 128) {
        float s = 0.f;
        for (int j = 0; j < 128; ++j)
            s = fmaf(q[j], ld(in_proj_b, 128 + j, isbf), s);
        red[10] = s;   // q . bk
    }
    __syncthreads();
    {   // logit for path p = tid
        float s = 0.f;
        const float* lp = g_last + ((size_t)b * 256 + tid) * H_;
        for (int u = 0; u < 128; ++u)
            s = fmaf(qk[u], lp[u], s);
        logits[tid] = (s + red[10]) * 0.08838834764831845f;  // 1/sqrt(128)
    }
    __syncthreads();
    float v = logits[tid];
    #pragma unroll
    for (int off = 32; off > 0; off >>= 1) v = fmaxf(v, __shfl_xor(v, off, 64));
    if ((tid & 63) == 0) red[tid >> 6] = v;
    __syncthreads();
    if (tid == 0) red[8] = fmaxf(fmaxf(red[0], red[1]), fmaxf(red[2], red[3]));
    __syncthreads();
    const float e = __expf(logits[tid] - red[8]);
    float sum = e;
    #pragma unroll
    for (int off = 32; off > 0; off >>= 1) sum += __shfl_xor(sum, off, 64);
    if ((tid & 63) == 0) red[4 + (tid >> 6)] = sum;
    __syncthreads();
    if (tid == 0) red[9] = red[4] + red[5] + red[6] + red[7];
    __syncthreads();
    logits[tid] = e / red[9];
    __syncthreads();
    {   // sv[u] = sum_p attn[p] * last[b,p,u]
        const int u = tid & 127, half = tid >> 7;
        float s = 0.f;
        const float* lb = g_last + ((size_t)b * 256 + half * 128) * H_ + u;
        for (int p = 0; p < 128; ++p)
            s = fmaf(logits[half * 128 + p], lb[(size_t)p * H_], s);
        sv2[half][u] = s;
    }
    __syncthreads();
    if (tid < 128) q[tid] = sv2[0][tid] + sv2[1][tid];   // reuse q[] as sv
    __syncthreads();
    if (tid < 128) {
        float s = 0.f;
        for (int u = 0; u < 128; ++u)
            s = fmaf(ld(in_proj_w, (size_t)(256 + tid) * 128 + u, isbf), q[u], s);
        ctx[tid] = s + ld(in_proj_b, 256 + tid, isbf);
    }
    __syncthreads();
    if (tid < 128) {
        float s = 0.f;
        for (int d = 0; d < 128; ++d)
            s = fmaf(ld(out_proj_w, (size_t)tid * 128 + d, isbf), ctx[d], s);
        out[b * 128 + tid] = s + ld(out_proj_b, tid, isbf);
    }
}

// ---------------------------------------------------------------------------
extern "C" void kernel_launch(void* const* d_in, const int* in_sizes, int n_in,
                              void* d_out, int out_size, void* d_ws, size_t ws_size,
                              hipStream_t stream)
{
    const void* graph_embed = d_in[0];
    const void* node_opt    = d_in[1];
    const void* rel_embeds  = d_in[2];
    const void* W_ih        = d_in[3];
    const void* W_hh        = d_in[4];
    const void* b_ih        = d_in[5];
    const void* b_hh        = d_in[6];
    const void* in_proj_w   = d_in[7];
    const void* in_proj_b   = d_in[8];
    const void* out_proj_w  = d_in[9];
    const void* out_proj_b  = d_in[10];
    const int* node_idx  = (const int*)d_in[11];
    const int* rel_idx   = (const int*)d_in[12];
    const int* path_lens = (const int*)d_in[13];
    (void)d_ws; (void)ws_size; (void)in_sizes; (void)n_in; (void)out_size;

    hipLaunchKernelGGL(k_detect, dim3(1), dim3(256), 0, stream, node_opt, node_idx);
    hipLaunchKernelGGL(k_prep, dim3(G4_), dim3(KB_), 0, stream, W_ih, W_hh, b_ih, b_hh);
    hipLaunchKernelGGL(k_sort, dim3(1), dim3(256), 0, stream, path_lens);
    hipLaunchKernelGGL(k_lstm, dim3(NPATH / NPB), dim3(256), 0, stream,
                       graph_embed, rel_embeds, node_idx, rel_idx, path_lens);
    hipLaunchKernelGGL(k_attn, dim3(B_), dim3(256), 0, stream,
                       node_opt, in_proj_w, in_proj_b, out_proj_w, out_proj_b,
                       (float*)d_out);
}

// Round 7
// 441.466 us; speedup vs baseline: 2.2780x; 1.0934x over previous
//
#include <hip/hip_runtime.h>
#include <hip/hip_bf16.h>

// B=32, N=4096, P=256, L=16, DR=128, H=128, NUM_REL=400.
// Contract (verified r5/r6): float inputs f32, ints int32, output f32 [32][128].
// r6: MFMA LSTM passed (absmax 6.1e-5), k_lstm 311us but MfmaUtil 3.5% —
// serial B-load->mfma chain at VGPR=72. r7: double-buffered B fragments +
// x-gather prefetch + __launch_bounds__(256,2); vectorized k_attn.

#define B_    32
#define N_    4096
#define L_    16
#define DR_   128
#define H_    128
#define G4_   512
#define KB_   384        // h(128) | node(128) | rel(128)
#define AST   392        // LDS A row stride in bf16 (784B, 16B-aligned)
#define NPATH 8192
#define NPB   16

typedef unsigned short bfraw;
typedef short short8 __attribute__((ext_vector_type(8)));
typedef float f32x4 __attribute__((ext_vector_type(4)));

__device__ int   g_isbf16;
__device__ int   g_isi64;
__device__ __align__(16) bfraw g_Wbf[G4_ * KB_];   // [512][384] bf16, row-major
__device__ float g_bias[G4_];
__device__ int   g_perm[NPATH];
__device__ float g_last[NPATH * H_];               // f32 [8192][128]

__device__ __forceinline__ float bfc(bfraw v) {
    return __uint_as_float(((unsigned)v) << 16);
}
__device__ __forceinline__ bfraw f2b(float f) {    // RNE f32->bf16
    unsigned u = __float_as_uint(f);
    return (bfraw)((u + 0x7FFFu + ((u >> 16) & 1u)) >> 16);
}
__device__ __forceinline__ unsigned pk2(float a, float b) {
    return (unsigned)f2b(a) | ((unsigned)f2b(b) << 16);
}
__device__ __forceinline__ float ld(const void* p, size_t i, int isbf) {
    return isbf ? bfc(((const bfraw*)p)[i]) : ((const float*)p)[i];
}
__device__ __forceinline__ float sigf(float x) { return 1.0f / (1.0f + __expf(-x)); }
__device__ __forceinline__ float tanhfast(float x) { return 2.0f * sigf(2.0f * x) - 1.0f; }

// dot of 128 contiguous f32 (global w) with 128 f32 in LDS
__device__ __forceinline__ float dot128(const float* __restrict__ w,
                                        const float* __restrict__ s) {
    float acc = 0.f;
    #pragma unroll
    for (int i = 0; i < 32; ++i) {
        const float4 wv = *(const float4*)(w + i * 4);
        acc = fmaf(wv.x, s[i*4+0], fmaf(wv.y, s[i*4+1],
              fmaf(wv.z, s[i*4+2], fmaf(wv.w, s[i*4+3], acc))));
    }
    return acc;
}

// ---------------------------------------------------------------------------
__global__ __launch_bounds__(256) void k_detect(const void* __restrict__ node_opt,
                                                const int*  __restrict__ node_idx)
{
    __shared__ int s_big, s_nz;
    const int tid = threadIdx.x;
    if (tid == 0) { s_big = 0; s_nz = 0; }
    __syncthreads();
    const unsigned short* u = (const unsigned short*)node_opt;
    int big = 0;
    for (int i = tid; i < 2048; i += 256) {
        const float v = fabsf(bfc(u[i]));
        big |= !(v < 1.0e3f);                 // NaN-safe
    }
    if (big) s_big = 1;
    int nz = 0;
    for (int i = tid; i < 512; i += 256) nz |= (node_idx[2 * i + 1] != 0);
    if (nz) s_nz = 1;
    __syncthreads();
    if (tid == 0) { g_isbf16 = s_big ? 0 : 1; g_isi64 = s_nz ? 0 : 1; }
}

// ---------------------------------------------------------------------------
// g_Wbf[j][k] = bf16( k<128 ? W_hh[j][k] : W_ih[j][k-128] )
__global__ __launch_bounds__(384) void k_prep(
    const void* __restrict__ W_ih, const void* __restrict__ W_hh,
    const void* __restrict__ b_ih, const void* __restrict__ b_hh)
{
    const int isbf = g_isbf16;
    const int j = blockIdx.x;          // 0..511
    const int k = threadIdx.x;         // 0..383
    const float v = (k < H_) ? ld(W_hh, (size_t)j * H_ + k, isbf)
                             : ld(W_ih, (size_t)j * 256 + (k - H_), isbf);
    g_Wbf[j * KB_ + k] = f2b(v);
    if (k == 0) g_bias[j] = ld(b_ih, j, isbf) + ld(b_hh, j, isbf);
}

// ---------------------------------------------------------------------------
__global__ __launch_bounds__(256) void k_sort(const int* __restrict__ path_lens)
{
    __shared__ int hist[16], cur[16];
    const int i64 = g_isi64;
    const int tid = threadIdx.x;
    if (tid < 16) hist[tid] = 0;
    __syncthreads();
    for (int p = tid; p < NPATH; p += 256) {
        const int len = i64 ? path_lens[2 * p] : path_lens[p];
        atomicAdd(&hist[len - 1], 1);
    }
    __syncthreads();
    if (tid == 0) {
        int off = 0;
        for (int b = 15; b >= 0; --b) { cur[b] = off; off += hist[b]; }
    }
    __syncthreads();
    for (int p = tid; p < NPATH; p += 256) {
        const int len = i64 ? path_lens[2 * p] : path_lens[p];
        const int pos = atomicAdd(&cur[len - 1], 1);
        g_perm[pos] = p;
    }
}

// ---------------------------------------------------------------------------
// MFMA LSTM: 512 blocks x 256 threads, 16 paths/block (M=16), N=512, K=384.
// Wave w owns n-tiles {gate*8 + 2w + sub}; lane-local cell update.
// B fragments double-buffered in regs; x-gather prefetched one step ahead.
__global__ __launch_bounds__(256, 2) void k_lstm(
    const void* __restrict__ graph_embed,   // [32][4096][128] f32 (or bf16)
    const void* __restrict__ rel_embeds,    // [400][128]
    const int*  __restrict__ node_idx,      // [8192][16]
    const int*  __restrict__ rel_idx,       // [8192][16]
    const int*  __restrict__ path_lens)     // [8192]
{
    __shared__ __align__(16) bfraw A[NPB][AST];   // [path][ h | node | rel ]
    __shared__ int s_pid[NPB], s_len[NPB];
    __shared__ int s_nid[NPB][L_], s_rid[NPB][L_];

    const int isbf = g_isbf16;
    const int i64  = g_isi64;
    const int tid  = threadIdx.x;

    if (tid < NPB) {
        const int pid = g_perm[blockIdx.x * NPB + tid];
        s_pid[tid] = pid;
        s_len[tid] = i64 ? path_lens[2 * pid] : path_lens[pid];
    }
    __syncthreads();
    {   // indices: 16 paths x 16 steps
        const int m = tid >> 4, t = tid & 15;
        const int idx = s_pid[m] * L_ + t;
        s_nid[m][t] = i64 ? node_idx[2 * idx] : node_idx[idx];
        s_rid[m][t] = i64 ? rel_idx[2 * idx]  : rel_idx[idx];
    }
    {   // zero h region (k<128)
        const int m = tid >> 4, i0 = (tid & 15) * 8;
        *(uint4*)&A[m][i0] = make_uint4(0, 0, 0, 0);
    }
    __syncthreads();

    int maxlen = 0;
    #pragma unroll
    for (int m = 0; m < NPB; ++m) maxlen = max(maxlen, s_len[m]);

    const int w    = tid >> 6;     // wave 0..3
    const int l    = tid & 63;
    const int quad = l >> 4;
    const int col  = l & 15;

    // B row pointers + bias for the 8 owned n-tiles (j = gate*2 + sub)
    const bfraw* bp[8];
    float bq[8];
    #pragma unroll
    for (int j = 0; j < 8; ++j) {
        const int gate = j >> 1, sub = j & 1;
        const int n = gate * 128 + w * 32 + sub * 16 + col;
        bp[j] = g_Wbf + (size_t)n * KB_ + quad * 8;
        bq[j] = g_bias[n];
    }
    const bfraw* ab = &A[col][quad * 8];   // A-operand base (m = lane&15)

    // ---- x-gather prefetch state (thread m=tid>>4 stages 8 elems at i0) ----
    const int pm  = tid >> 4;
    const int pi0 = (tid & 15) * 8;
    const size_t gbase = (size_t)(s_pid[pm] >> 8) * (size_t)(N_ * DR_);
    uint4 pn0, pn1, pr0, pr1;

    auto issue_pf = [&](int t) {
        const int nid = s_nid[pm][t], rid = s_rid[pm][t];
        if (isbf) {
            pn0 = *(const uint4*)((const bfraw*)graph_embed + gbase + (size_t)nid * DR_ + pi0);
            pr0 = *(const uint4*)((const bfraw*)rel_embeds + (size_t)rid * DR_ + pi0);
        } else {
            const float* gp = (const float*)graph_embed + gbase + (size_t)nid * DR_ + pi0;
            pn0 = *(const uint4*)gp; pn1 = *(const uint4*)(gp + 4);
            const float* rp = (const float*)rel_embeds + (size_t)rid * DR_ + pi0;
            pr0 = *(const uint4*)rp; pr1 = *(const uint4*)(rp + 4);
        }
    };
    auto commit_pf = [&](int t) {
        const int len = s_len[pm];
        uint4 npk = make_uint4(0, 0, 0, 0), rpk = make_uint4(0, 0, 0, 0);
        if (t < len) {
            if (isbf) npk = pn0;
            else {
                const float* a = (const float*)&pn0;
                const float* b = (const float*)&pn1;
                npk = make_uint4(pk2(a[0],a[1]), pk2(a[2],a[3]),
                                 pk2(b[0],b[1]), pk2(b[2],b[3]));
            }
        }
        if (t < len - 1) {
            if (isbf) rpk = pr0;
            else {
                const float* a = (const float*)&pr0;
                const float* b = (const float*)&pr1;
                rpk = make_uint4(pk2(a[0],a[1]), pk2(a[2],a[3]),
                                 pk2(b[0],b[1]), pk2(b[2],b[3]));
            }
        }
        *(uint4*)&A[pm][128 + pi0] = npk;
        *(uint4*)&A[pm][256 + pi0] = rpk;
    };

    float c[2][4];
    #pragma unroll
    for (int s = 0; s < 2; ++s)
        #pragma unroll
        for (int r = 0; r < 4; ++r) c[s][r] = 0.f;

    issue_pf(0);
    for (int t = 0; t < maxlen; ++t) {
        commit_pf(t);          // write prefetched x into LDS (waits its vmcnt)
        __syncthreads();       // h(t-1) + x(t) visible to all

        if (t + 1 < maxlen) issue_pf(t + 1);   // block-uniform branch

        // ---- MFMA: D[m][n] += sum_k A[m][k] * W[n][k], K=384 ----
        f32x4 acc[8];
        #pragma unroll
        for (int j = 0; j < 8; ++j) {
            const float b = bq[j];
            acc[j][0] = b; acc[j][1] = b; acc[j][2] = b; acc[j][3] = b;
        }
        short8 breg[2][8];
        #pragma unroll
        for (int j = 0; j < 8; ++j) breg[0][j] = *(const short8*)(bp[j]);
        #pragma unroll
        for (int ks = 0; ks < KB_ / 32; ++ks) {
            const int cur = ks & 1, nxt = cur ^ 1;
            if (ks + 1 < KB_ / 32) {
                #pragma unroll
                for (int j = 0; j < 8; ++j)
                    breg[nxt][j] = *(const short8*)(bp[j] + (ks + 1) * 32);
            }
            const short8 a = *(const short8*)(ab + ks * 32);
            #pragma unroll
            for (int j = 0; j < 8; ++j)
                acc[j] = __builtin_amdgcn_mfma_f32_16x16x32_bf16(a, breg[cur][j], acc[j], 0, 0, 0);
        }
        __syncthreads();   // all A reads done before h overwrite

        // ---- lane-local gates + cell update + h write ----
        #pragma unroll
        for (int sub = 0; sub < 2; ++sub) {
            const int u = w * 32 + sub * 16 + col;
            #pragma unroll
            for (int r = 0; r < 4; ++r) {
                const int m = quad * 4 + r;
                const float ig = sigf(acc[0 + sub][r]);
                const float fg = sigf(acc[2 + sub][r]);
                const float gg = tanhfast(acc[4 + sub][r]);
                const float og = sigf(acc[6 + sub][r]);
                const float cc = fg * c[sub][r] + ig * gg;
                c[sub][r] = cc;
                const float h = og * tanhfast(cc);
                A[m][u] = f2b(h);
                if (t == s_len[m] - 1)
                    g_last[(size_t)s_pid[m] * H_ + u] = h;
            }
        }
        // h-writes (k<128) and next commit_pf (k>=128) are disjoint; the
        // barrier at the top of the next iteration orders them vs reads.
    }
}

// ---------------------------------------------------------------------------
// Attention epilogue, one block per batch element. f32 path vectorized.
__global__ __launch_bounds__(256) void k_attn(
    const void* __restrict__ node_opt,    // [32][128]
    const void* __restrict__ in_proj_w,   // [384][128]
    const void* __restrict__ in_proj_b,   // [384]
    const void* __restrict__ out_proj_w,  // [128][128]
    const void* __restrict__ out_proj_b,  // [128]
    float* __restrict__ out)              // [32][128] f32
{
    const int isbf = g_isbf16;
    const int b = blockIdx.x, tid = threadIdx.x;
    __shared__ __align__(16) float s_no[128], q[128], qk[128], sv2[2][128], ctx[128];
    __shared__ float logits[256];
    __shared__ float red[12];

    if (tid < 128) s_no[tid] = ld(node_opt, b * 128 + tid, isbf);
    __syncthreads();
    if (tid < 128) {
        float s;
        if (isbf) {
            s = 0.f;
            for (int j = 0; j < 128; ++j)
                s = fmaf(s_no[j], ld(in_proj_w, (size_t)tid * 128 + j, 1), s);
        } else {
            s = dot128((const float*)in_proj_w + (size_t)tid * 128, s_no);
        }
        q[tid] = s + ld(in_proj_b, tid, isbf);
    }
    __syncthreads();
    if (tid < 128) {   // qk[u] = sum_j q[j] * Wk[j][u]  (coalesced across tid)
        float s = 0.f;
        for (int j = 0; j < 128; ++j)
            s = fmaf(q[j], ld(in_proj_w, (size_t)(128 + j) * 128 + tid, isbf), s);
        qk[tid] = s;
    } else if (tid == 128) {
        float s = 0.f;
        for (int j = 0; j < 128; ++j)
            s = fmaf(q[j], ld(in_proj_b, 128 + j, isbf), s);
        red[10] = s;   // q . bk
    }
    __syncthreads();
    {   // logit for path p = tid
        const float* lp = g_last + ((size_t)b * 256 + tid) * H_;
        const float s = dot128(lp, qk);
        logits[tid] = (s + red[10]) * 0.08838834764831845f;  // 1/sqrt(128)
    }
    __syncthreads();
    float v = logits[tid];
    #pragma unroll
    for (int off = 32; off > 0; off >>= 1) v = fmaxf(v, __shfl_xor(v, off, 64));
    if ((tid & 63) == 0) red[tid >> 6] = v;
    __syncthreads();
    if (tid == 0) red[8] = fmaxf(fmaxf(red[0], red[1]), fmaxf(red[2], red[3]));
    __syncthreads();
    const float e = __expf(logits[tid] - red[8]);
    float sum = e;
    #pragma unroll
    for (int off = 32; off > 0; off >>= 1) sum += __shfl_xor(sum, off, 64);
    if ((tid & 63) == 0) red[4 + (tid >> 6)] = sum;
    __syncthreads();
    if (tid == 0) red[9] = red[4] + red[5] + red[6] + red[7];
    __syncthreads();
    logits[tid] = e / red[9];
    __syncthreads();
    {   // sv[u] = sum_p attn[p] * last[b,p,u]  (coalesced across tid)
        const int u = tid & 127, half = tid >> 7;
        float s = 0.f;
        const float* lb = g_last + ((size_t)b * 256 + half * 128) * H_ + u;
        for (int p = 0; p < 128; ++p)
            s = fmaf(logits[half * 128 + p], lb[(size_t)p * H_], s);
        sv2[half][u] = s;
    }
    __syncthreads();
    if (tid < 128) q[tid] = sv2[0][tid] + sv2[1][tid];   // reuse q[] as sv
    __syncthreads();
    if (tid < 128) {
        float s;
        if (isbf) {
            s = 0.f;
            for (int u = 0; u < 128; ++u)
                s = fmaf(q[u], ld(in_proj_w, (size_t)(256 + tid) * 128 + u, 1), s);
        } else {
            s = dot128((const float*)in_proj_w + (size_t)(256 + tid) * 128, q);
        }
        ctx[tid] = s + ld(in_proj_b, 256 + tid, isbf);
    }
    __syncthreads();
    if (tid < 128) {
        float s;
        if (isbf) {
            s = 0.f;
            for (int d = 0; d < 128; ++d)
                s = fmaf(ctx[d], ld(out_proj_w, (size_t)tid * 128 + d, 1), s);
        } else {
            s = dot128((const float*)out_proj_w + (size_t)tid * 128, ctx);
        }
        out[b * 128 + tid] = s + ld(out_proj_b, tid, isbf);
    }
}

// ---------------------------------------------------------------------------
extern "C" void kernel_launch(void* const* d_in, const int* in_sizes, int n_in,
                              void* d_out, int out_size, void* d_ws, size_t ws_size,
                              hipStream_t stream)
{
    const void* graph_embed = d_in[0];
    const void* node_opt    = d_in[1];
    const void* rel_embeds  = d_in[2];
    const void* W_ih        = d_in[3];
    const void* W_hh        = d_in[4];
    const void* b_ih        = d_in[5];
    const void* b_hh        = d_in[6];
    const void* in_proj_w   = d_in[7];
    const void* in_proj_b   = d_in[8];
    const void* out_proj_w  = d_in[9];
    const void* out_proj_b  = d_in[10];
    const int* node_idx  = (const int*)d_in[11];
    const int* rel_idx   = (const int*)d_in[12];
    const int* path_lens = (const int*)d_in[13];
    (void)d_ws; (void)ws_size; (void)in_sizes; (void)n_in; (void)out_size;

    hipLaunchKernelGGL(k_detect, dim3(1), dim3(256), 0, stream, node_opt, node_idx);
    hipLaunchKernelGGL(k_prep, dim3(G4_), dim3(KB_), 0, stream, W_ih, W_hh, b_ih, b_hh);
    hipLaunchKernelGGL(k_sort, dim3(1), dim3(256), 0, stream, path_lens);
    hipLaunchKernelGGL(k_lstm, dim3(NPATH / NPB), dim3(256), 0, stream,
                       graph_embed, rel_embeds, node_idx, rel_idx, path_lens);
    hipLaunchKernelGGL(k_attn, dim3(B_), dim3(256), 0, stream,
                       node_opt, in_proj_w, in_proj_b, out_proj_w, out_proj_b,
                       (float*)d_out);
}

// Round 8
// 360.537 us; speedup vs baseline: 2.7893x; 1.2245x over previous
//
#include <hip/hip_runtime.h>
#include <hip/hip_bf16.h>

// B=32, N=4096, P=256, L=16, DR=128, H=128, NUM_REL=400.
// Contract (verified r5-r7): float inputs f32, ints int32, output f32 [32][128].
// r8: LDS-staged W pipeline. K=256=[h|node] (rel folded into f32 rel_proj,
// added in epilogue). NPB=32, 512 threads, 256 blocks (1/CU). W repacked to
// chunk layout [ck][qk][n][8] bf16; per step 8x32KB chunks stream
// global->regs->LDS (coalesced, 8-wave deep) while MFMA consumes the
// previous chunk from LDS (conflict-free ds_read_b128).

#define B_    32
#define N_    4096
#define L_    16
#define DR_   128
#define H_    128
#define G4_   512
#define KC_   256        // GEMM K: h(128) | node(128)
#define AST2  264        // A row stride in bf16 elems (528B, 16B-aligned)
#define NPATH 8192
#define NPB   32

typedef unsigned short bfraw;
typedef short short8 __attribute__((ext_vector_type(8)));
typedef float f32x4 __attribute__((ext_vector_type(4)));

__device__ int   g_isbf16;
__device__ int   g_isi64;
__device__ __align__(16) bfraw g_Wrep[8 * 2048 * 8]; // [ck][qk*512+n][8] bf16, 256KB
__device__ float g_relproj[400 * G4_];               // [400][512] f32
__device__ float g_bias[G4_];
__device__ int   g_perm[NPATH];
__device__ float g_last[NPATH * H_];                 // f32 [8192][128]

__device__ __forceinline__ float bfc(bfraw v) {
    return __uint_as_float(((unsigned)v) << 16);
}
__device__ __forceinline__ bfraw f2b(float f) {      // RNE f32->bf16
    unsigned u = __float_as_uint(f);
    return (bfraw)((u + 0x7FFFu + ((u >> 16) & 1u)) >> 16);
}
__device__ __forceinline__ unsigned pk2(float a, float b) {
    return (unsigned)f2b(a) | ((unsigned)f2b(b) << 16);
}
__device__ __forceinline__ float ld(const void* p, size_t i, int isbf) {
    return isbf ? bfc(((const bfraw*)p)[i]) : ((const float*)p)[i];
}
__device__ __forceinline__ float sigf(float x) { return 1.0f / (1.0f + __expf(-x)); }
__device__ __forceinline__ float tanhfast(float x) { return 2.0f * sigf(2.0f * x) - 1.0f; }

// dot of 128 contiguous f32 (global w) with 128 f32 in LDS
__device__ __forceinline__ float dot128(const float* __restrict__ w,
                                        const float* __restrict__ s) {
    float acc = 0.f;
    #pragma unroll
    for (int i = 0; i < 32; ++i) {
        const float4 wv = *(const float4*)(w + i * 4);
        acc = fmaf(wv.x, s[i*4+0], fmaf(wv.y, s[i*4+1],
              fmaf(wv.z, s[i*4+2], fmaf(wv.w, s[i*4+3], acc))));
    }
    return acc;
}

// ---------------------------------------------------------------------------
// Setup: dtype detect + bias + counting sort (one block, 512 threads).
__global__ __launch_bounds__(512) void k_setup(
    const void* __restrict__ node_opt, const int* __restrict__ node_idx,
    const void* __restrict__ b_ih, const void* __restrict__ b_hh,
    const int* __restrict__ path_lens)
{
    __shared__ int s_big, s_nz, s_isbf, s_i64, hist[16], cur[16];
    const int tid = threadIdx.x;
    if (tid == 0) { s_big = 0; s_nz = 0; }
    if (tid < 16) hist[tid] = 0;
    __syncthreads();
    {
        const unsigned short* u = (const unsigned short*)node_opt;
        int big = 0;
        for (int i = tid; i < 2048; i += 512) {
            const float v = fabsf(bfc(u[i]));
            big |= !(v < 1.0e3f);             // NaN-safe
        }
        if (big) s_big = 1;
        int nz = 0;
        if (tid < 512) nz |= (node_idx[2 * tid + 1] != 0);
        if (nz) s_nz = 1;
    }
    __syncthreads();
    if (tid == 0) {
        s_isbf = s_big ? 0 : 1;  s_i64 = s_nz ? 0 : 1;
        g_isbf16 = s_isbf;       g_isi64 = s_i64;
    }
    __syncthreads();
    const int isbf = s_isbf, i64 = s_i64;
    g_bias[tid] = ld(b_ih, tid, isbf) + ld(b_hh, tid, isbf);   // tid<512
    for (int p = tid; p < NPATH; p += 512) {
        const int len = i64 ? path_lens[2 * p] : path_lens[p];
        atomicAdd(&hist[len - 1], 1);
    }
    __syncthreads();
    if (tid == 0) {
        int off = 0;
        for (int b = 15; b >= 0; --b) { cur[b] = off; off += hist[b]; }
    }
    __syncthreads();
    for (int p = tid; p < NPATH; p += 512) {
        const int len = i64 ? path_lens[2 * p] : path_lens[p];
        const int pos = atomicAdd(&cur[len - 1], 1);
        g_perm[pos] = p;
    }
}

// ---------------------------------------------------------------------------
// rel_proj[r][n] = sum_d rel_embeds[r][d] * W_ih[n][128+d]   (f32)
__global__ __launch_bounds__(256) void k_relproj(
    const void* __restrict__ rel_embeds, const void* __restrict__ W_ih)
{
    __shared__ float relv[DR_];
    const int isbf = g_isbf16;
    const int r = blockIdx.x;          // 0..399
    const int tid = threadIdx.x;
    if (tid < DR_) relv[tid] = ld(rel_embeds, (size_t)r * DR_ + tid, isbf);
    __syncthreads();
    float s0 = 0.f, s1 = 0.f;
    for (int d = 0; d < DR_; ++d) {
        const float rv = relv[d];
        s0 = fmaf(rv, ld(W_ih, (size_t)tid * 256 + DR_ + d, isbf), s0);
        s1 = fmaf(rv, ld(W_ih, (size_t)(tid + 256) * 256 + DR_ + d, isbf), s1);
    }
    g_relproj[r * G4_ + tid]       = s0;
    g_relproj[r * G4_ + 256 + tid] = s1;
}

// ---------------------------------------------------------------------------
// Repack W into chunk layout: unit u = (ck*4+qk)*512 + n holds bf16 of
// W_cat[n][ck*32+qk*8 .. +8], where W_cat[n][k] = k<128 ? W_hh[n][k]
// : W_ih[n][k-128] (node cols). Grid 32 blocks = (ck,qk), 512 threads = n.
__global__ __launch_bounds__(512) void k_wrep(
    const void* __restrict__ W_ih, const void* __restrict__ W_hh)
{
    const int isbf = g_isbf16;
    const int ck = blockIdx.x >> 2, qk = blockIdx.x & 3;
    const int n  = threadIdx.x;
    const int k0 = ck * 32 + qk * 8;
    bfraw v[8];
    #pragma unroll
    for (int j = 0; j < 8; ++j) {
        const int k = k0 + j;
        const float f = (k < H_) ? ld(W_hh, (size_t)n * H_ + k, isbf)
                                 : ld(W_ih, (size_t)n * 256 + (k - H_), isbf);
        v[j] = f2b(f);
    }
    *(uint4*)&g_Wrep[(size_t)(((ck * 4 + qk) * 512) + n) * 8] = *(uint4*)v;
}

// ---------------------------------------------------------------------------
// MFMA LSTM: 256 blocks x 512 threads, 32 paths/block, N=512, K=256.
// Wave w (0..7) owns units u = w*16+col for all 4 gates; 2 m-tiles.
// W streamed as 8x32KB chunks through a 2-buffer LDS pipeline.
__global__ __launch_bounds__(512, 2) void k_lstm(
    const void* __restrict__ graph_embed,   // [32][4096][128] f32 (or bf16)
    const int*  __restrict__ node_idx,      // [8192][16]
    const int*  __restrict__ rel_idx,       // [8192][16]
    const int*  __restrict__ path_lens)     // [8192]
{
    __shared__ __align__(16) bfraw A[NPB][AST2];    // [path][ h(0:128) | node(128:256) ]
    __shared__ __align__(16) bfraw Wb[2][16384];    // 2 x 32KB W chunks
    __shared__ int s_pid[NPB], s_len[NPB];
    __shared__ int s_nid[NPB][L_], s_rid[NPB][L_];

    const int isbf = g_isbf16;
    const int i64  = g_isi64;
    const int tid  = threadIdx.x;

    if (tid < NPB) {
        const int pid = g_perm[blockIdx.x * NPB + tid];
        s_pid[tid] = pid;
        s_len[tid] = i64 ? path_lens[2 * pid] : path_lens[pid];
    }
    __syncthreads();
    {   // indices: 512 threads = 32 paths x 16 steps
        const int m = tid >> 4, t = tid & 15;
        const int idx = s_pid[m] * L_ + t;
        s_nid[m][t] = i64 ? node_idx[2 * idx] : node_idx[idx];
        s_rid[m][t] = i64 ? rel_idx[2 * idx]  : rel_idx[idx];
    }
    {   // zero h region (k<128): 32 rows x 128 bf16
        const int m = tid >> 4, i0 = (tid & 15) * 8;
        *(uint4*)&A[m][i0] = make_uint4(0, 0, 0, 0);
    }
    __syncthreads();

    int maxlen = 0;
    #pragma unroll
    for (int m = 0; m < NPB; ++m) maxlen = max(maxlen, s_len[m]);

    const int w    = tid >> 6;     // wave 0..7
    const int l    = tid & 63;
    const int quad = l >> 4;
    const int col  = l & 15;
    const int u0   = w * 16 + col; // owned unit

    int bo[4];                     // B-frag LDS elem offsets per gate
    float bq4[4];
    #pragma unroll
    for (int g = 0; g < 4; ++g) {
        bo[g]  = (quad * 512 + g * 128 + u0) * 8;
        bq4[g] = g_bias[g * 128 + u0];
    }

    // x-gather prefetch (thread pm stages 8 node elems at pi0)
    const int pm  = tid >> 4;
    const int pi0 = (tid & 15) * 8;
    const size_t gbase = (size_t)(s_pid[pm] >> 8) * (size_t)(N_ * DR_);
    uint4 pn0, pn1;

    const uint4* wrep = (const uint4*)g_Wrep;

    // issue prefetch for t=0
    {
        const int nid = s_nid[pm][0];
        if (isbf) {
            pn0 = *(const uint4*)((const bfraw*)graph_embed + gbase + (size_t)nid * DR_ + pi0);
        } else {
            const float* gp = (const float*)graph_embed + gbase + (size_t)nid * DR_ + pi0;
            pn0 = *(const uint4*)gp; pn1 = *(const uint4*)(gp + 4);
        }
    }
    // stage chunk 0 into Wb[0]
    {
        uint4 sv[4];
        #pragma unroll
        for (int j = 0; j < 4; ++j) sv[j] = wrep[tid + j * 512];
        #pragma unroll
        for (int j = 0; j < 4; ++j) *(uint4*)&Wb[0][(tid + j * 512) * 8] = sv[j];
    }

    float c[2][4];
    #pragma unroll
    for (int mt = 0; mt < 2; ++mt)
        #pragma unroll
        for (int r = 0; r < 4; ++r) c[mt][r] = 0.f;

    for (int t = 0; t < maxlen; ++t) {
        // ---- commit prefetched node x(t) into A (masked) ----
        {
            uint4 npk = make_uint4(0, 0, 0, 0);
            if (t < s_len[pm]) {
                if (isbf) npk = pn0;
                else {
                    const float* a = (const float*)&pn0;
                    const float* b = (const float*)&pn1;
                    npk = make_uint4(pk2(a[0],a[1]), pk2(a[2],a[3]),
                                     pk2(b[0],b[1]), pk2(b[2],b[3]));
                }
            }
            *(uint4*)&A[pm][128 + pi0] = npk;
        }
        // ---- issue prefetch for t+1 (block-uniform branch) ----
        if (t + 1 < maxlen) {
            const int nid = s_nid[pm][t + 1];
            if (isbf) {
                pn0 = *(const uint4*)((const bfraw*)graph_embed + gbase + (size_t)nid * DR_ + pi0);
            } else {
                const float* gp = (const float*)graph_embed + gbase + (size_t)nid * DR_ + pi0;
                pn0 = *(const uint4*)gp; pn1 = *(const uint4*)(gp + 4);
            }
        }
        // ---- early rel_proj gathers (consumed in epilogue) ----
        float rl[2][4][4];
        #pragma unroll
        for (int mt = 0; mt < 2; ++mt)
            #pragma unroll
            for (int r = 0; r < 4; ++r) {
                const int m = mt * 16 + quad * 4 + r;
                const float* rp = g_relproj + (size_t)s_rid[m][t] * G4_ + u0;
                #pragma unroll
                for (int g = 0; g < 4; ++g) rl[mt][g][r] = rp[g * 128];
            }

        // ---- accumulators ----
        f32x4 acc[2][4];
        #pragma unroll
        for (int mt = 0; mt < 2; ++mt)
            #pragma unroll
            for (int g = 0; g < 4; ++g) {
                const float b = bq4[g];
                acc[mt][g][0] = b; acc[mt][g][1] = b;
                acc[mt][g][2] = b; acc[mt][g][3] = b;
            }

        // ---- chunk pipeline: compute ck from Wb[ck&1], stage ck+1 ----
        for (int ck = 0; ck < 8; ++ck) {
            __syncthreads();     // Wb[ck&1] holds chunk ck; ck==0 also orders A
            const int nck = (ck + 1) & 7;
            uint4 sv[4];
            #pragma unroll
            for (int j = 0; j < 4; ++j) sv[j] = wrep[nck * 2048 + tid + j * 512];

            const bfraw* wb = Wb[ck & 1];
            const short8 a0 = *(const short8*)&A[col][ck * 32 + quad * 8];
            const short8 a1 = *(const short8*)&A[16 + col][ck * 32 + quad * 8];
            #pragma unroll
            for (int g = 0; g < 4; ++g) {
                const short8 b = *(const short8*)(wb + bo[g]);
                acc[0][g] = __builtin_amdgcn_mfma_f32_16x16x32_bf16(a0, b, acc[0][g], 0, 0, 0);
                acc[1][g] = __builtin_amdgcn_mfma_f32_16x16x32_bf16(a1, b, acc[1][g], 0, 0, 0);
            }
            #pragma unroll
            for (int j = 0; j < 4; ++j)
                *(uint4*)&Wb[(ck + 1) & 1][(tid + j * 512) * 8] = sv[j];
        }
        __syncthreads();         // all A reads done before h overwrite

        // ---- gates + cell update + h write + snapshot ----
        #pragma unroll
        for (int mt = 0; mt < 2; ++mt)
            #pragma unroll
            for (int r = 0; r < 4; ++r) {
                const int m = mt * 16 + quad * 4 + r;
                const float relm = (t < s_len[m] - 1) ? 1.0f : 0.0f;
                const float ig = sigf(acc[mt][0][r] + relm * rl[mt][0][r]);
                const float fg = sigf(acc[mt][1][r] + relm * rl[mt][1][r]);
                const float gg = tanhfast(acc[mt][2][r] + relm * rl[mt][2][r]);
                const float og = sigf(acc[mt][3][r] + relm * rl[mt][3][r]);
                const float cc = fg * c[mt][r] + ig * gg;
                c[mt][r] = cc;
                const float h = og * tanhfast(cc);
                A[m][u0] = f2b(h);
                if (t == s_len[m] - 1)
                    g_last[(size_t)s_pid[m] * H_ + u0] = h;
            }
        // h-writes (k<128) and next x-commit (k>=128) precede next ck0 barrier.
    }
}

// ---------------------------------------------------------------------------
// Attention epilogue, one block per batch element (r7 version).
__global__ __launch_bounds__(256) void k_attn(
    const void* __restrict__ node_opt,    // [32][128]
    const void* __restrict__ in_proj_w,   // [384][128]
    const void* __restrict__ in_proj_b,   // [384]
    const void* __restrict__ out_proj_w,  // [128][128]
    const void* __restrict__ out_proj_b,  // [128]
    float* __restrict__ out)              // [32][128] f32
{
    const int isbf = g_isbf16;
    const int b = blockIdx.x, tid = threadIdx.x;
    __shared__ __align__(16) float s_no[128], q[128], qk[128], sv2[2][128], ctx[128];
    __shared__ float logits[256];
    __shared__ float red[12];

    if (tid < 128) s_no[tid] = ld(node_opt, b * 128 + tid, isbf);
    __syncthreads();
    if (tid < 128) {
        float s;
        if (isbf) {
            s = 0.f;
            for (int j = 0; j < 128; ++j)
                s = fmaf(s_no[j], ld(in_proj_w, (size_t)tid * 128 + j, 1), s);
        } else {
            s = dot128((const float*)in_proj_w + (size_t)tid * 128, s_no);
        }
        q[tid] = s + ld(in_proj_b, tid, isbf);
    }
    __syncthreads();
    if (tid < 128) {   // qk[u] = sum_j q[j] * Wk[j][u]
        float s = 0.f;
        for (int j = 0; j < 128; ++j)
            s = fmaf(q[j], ld(in_proj_w, (size_t)(128 + j) * 128 + tid, isbf), s);
        qk[tid] = s;
    } else if (tid == 128) {
        float s = 0.f;
        for (int j = 0; j < 128; ++j)
            s = fmaf(q[j], ld(in_proj_b, 128 + j, isbf), s);
        red[10] = s;   // q . bk
    }
    __syncthreads();
    {   // logit for path p = tid
        const float* lp = g_last + ((size_t)b * 256 + tid) * H_;
        const float s = dot128(lp, qk);
        logits[tid] = (s + red[10]) * 0.08838834764831845f;  // 1/sqrt(128)
    }
    __syncthreads();
    float v = logits[tid];
    #pragma unroll
    for (int off = 32; off > 0; off >>= 1) v = fmaxf(v, __shfl_xor(v, off, 64));
    if ((tid & 63) == 0) red[tid >> 6] = v;
    __syncthreads();
    if (tid == 0) red[8] = fmaxf(fmaxf(red[0], red[1]), fmaxf(red[2], red[3]));
    __syncthreads();
    const float e = __expf(logits[tid] - red[8]);
    float sum = e;
    #pragma unroll
    for (int off = 32; off > 0; off >>= 1) sum += __shfl_xor(sum, off, 64);
    if ((tid & 63) == 0) red[4 + (tid >> 6)] = sum;
    __syncthreads();
    if (tid == 0) red[9] = red[4] + red[5] + red[6] + red[7];
    __syncthreads();
    logits[tid] = e / red[9];
    __syncthreads();
    {   // sv[u] = sum_p attn[p] * last[b,p,u]
        const int u = tid & 127, half = tid >> 7;
        float s = 0.f;
        const float* lb = g_last + ((size_t)b * 256 + half * 128) * H_ + u;
        for (int p = 0; p < 128; ++p)
            s = fmaf(logits[half * 128 + p], lb[(size_t)p * H_], s);
        sv2[half][u] = s;
    }
    __syncthreads();
    if (tid < 128) q[tid] = sv2[0][tid] + sv2[1][tid];   // reuse q[] as sv
    __syncthreads();
    if (tid < 128) {
        float s;
        if (isbf) {
            s = 0.f;
            for (int u = 0; u < 128; ++u)
                s = fmaf(q[u], ld(in_proj_w, (size_t)(256 + tid) * 128 + u, 1), s);
        } else {
            s = dot128((const float*)in_proj_w + (size_t)(256 + tid) * 128, q);
        }
        ctx[tid] = s + ld(in_proj_b, 256 + tid, isbf);
    }
    __syncthreads();
    if (tid < 128) {
        float s;
        if (isbf) {
            s = 0.f;
            for (int d = 0; d < 128; ++d)
                s = fmaf(ctx[d], ld(out_proj_w, (size_t)tid * 128 + d, 1), s);
        } else {
            s = dot128((const float*)out_proj_w + (size_t)tid * 128, ctx);
        }
        out[b * 128 + tid] = s + ld(out_proj_b, tid, isbf);
    }
}

// ---------------------------------------------------------------------------
extern "C" void kernel_launch(void* const* d_in, const int* in_sizes, int n_in,
                              void* d_out, int out_size, void* d_ws, size_t ws_size,
                              hipStream_t stream)
{
    const void* graph_embed = d_in[0];
    const void* node_opt    = d_in[1];
    const void* rel_embeds  = d_in[2];
    const void* W_ih        = d_in[3];
    const void* W_hh        = d_in[4];
    const void* b_ih        = d_in[5];
    const void* b_hh        = d_in[6];
    const void* in_proj_w   = d_in[7];
    const void* in_proj_b   = d_in[8];
    const void* out_proj_w  = d_in[9];
    const void* out_proj_b  = d_in[10];
    const int* node_idx  = (const int*)d_in[11];
    const int* rel_idx   = (const int*)d_in[12];
    const int* path_lens = (const int*)d_in[13];
    (void)d_ws; (void)ws_size; (void)in_sizes; (void)n_in; (void)out_size;

    hipLaunchKernelGGL(k_setup, dim3(1), dim3(512), 0, stream,
                       node_opt, node_idx, b_ih, b_hh, path_lens);
    hipLaunchKernelGGL(k_relproj, dim3(400), dim3(256), 0, stream, rel_embeds, W_ih);
    hipLaunchKernelGGL(k_wrep, dim3(32), dim3(512), 0, stream, W_ih, W_hh);
    hipLaunchKernelGGL(k_lstm, dim3(NPATH / NPB), dim3(512), 0, stream,
                       graph_embed, node_idx, rel_idx, path_lens);
    hipLaunchKernelGGL(k_attn, dim3(B_), dim3(256), 0, stream,
                       node_opt, in_proj_w, in_proj_b, out_proj_w, out_proj_b,
                       (float*)d_out);
}

// Round 9
// 233.503 us; speedup vs baseline: 4.3069x; 1.5440x over previous
//
#include <hip/hip_runtime.h>
#include <hip/hip_bf16.h>

// B=32, N=4096, P=256, L=16, DR=128, H=128, NUM_REL=400.
// Contract (verified r5-r8): float inputs f32, ints int32, output f32 [32][128].
// r9: W-in-registers MFMA LSTM. Full bf16 W (512x256 = 256KB) lives in
// 128 VGPRs/lane across 8 waves (8 K-chunks x 4 gates x 16B); K-loop is
// ds_read_b128(A) + MFMA only, 2 barriers/step. Prep fused into one kernel
// (400 relproj blocks + 256 W-repack blocks + 1 bias/detect/sort block),
// relproj now coalescing-friendly float4. 3 launches total.

#define B_    32
#define N_    4096
#define L_    16
#define DR_   128
#define H_    128
#define G4_   512
#define AST2  264        // A row stride in bf16 elems (528B, 16B-aligned)
#define NPATH 8192
#define NPB   32

typedef unsigned short bfraw;
typedef short short8 __attribute__((ext_vector_type(8)));
typedef float f32x4 __attribute__((ext_vector_type(4)));

__device__ int   g_isbf16;
__device__ int   g_isi64;
__device__ __align__(16) bfraw g_Wcat[G4_ * 256];    // [n][k] bf16, 256KB
__device__ float g_relproj[400 * G4_];               // [400][512] f32
__device__ float g_bias[G4_];
__device__ int   g_perm[NPATH];
__device__ float g_last[NPATH * H_];                 // f32 [8192][128]

__device__ __forceinline__ float bfc(bfraw v) {
    return __uint_as_float(((unsigned)v) << 16);
}
__device__ __forceinline__ bfraw f2b(float f) {      // RNE f32->bf16
    unsigned u = __float_as_uint(f);
    return (bfraw)((u + 0x7FFFu + ((u >> 16) & 1u)) >> 16);
}
__device__ __forceinline__ unsigned pk2(float a, float b) {
    return (unsigned)f2b(a) | ((unsigned)f2b(b) << 16);
}
__device__ __forceinline__ float ld(const void* p, size_t i, int isbf) {
    return isbf ? bfc(((const bfraw*)p)[i]) : ((const float*)p)[i];
}
__device__ __forceinline__ float sigf(float x) { return 1.0f / (1.0f + __expf(-x)); }
__device__ __forceinline__ float tanhfast(float x) { return 2.0f * sigf(2.0f * x) - 1.0f; }

// dot of 128 contiguous f32 (global w) with 128 f32 in LDS
__device__ __forceinline__ float dot128(const float* __restrict__ w,
                                        const float* __restrict__ s) {
    float acc = 0.f;
    #pragma unroll
    for (int i = 0; i < 32; ++i) {
        const float4 wv = *(const float4*)(w + i * 4);
        acc = fmaf(wv.x, s[i*4+0], fmaf(wv.y, s[i*4+1],
              fmaf(wv.z, s[i*4+2], fmaf(wv.w, s[i*4+3], acc))));
    }
    return acc;
}

// ---------------------------------------------------------------------------
// Fused prep, grid 657 x 512 threads:
//   blocks 0..399   : rel_proj row r = blockIdx
//   blocks 400..655 : W repack chunk (256 x 512 elems)
//   block  656      : detect flags + bias + counting sort
// Each block detects the float dtype locally (no cross-block dependency).
__global__ __launch_bounds__(512) void k_prep(
    const void* __restrict__ node_opt, const int* __restrict__ node_idx,
    const void* __restrict__ rel_embeds,
    const void* __restrict__ W_ih, const void* __restrict__ W_hh,
    const void* __restrict__ b_ih, const void* __restrict__ b_hh,
    const int* __restrict__ path_lens)
{
    __shared__ float relv[DR_];
    __shared__ int s_big, s_nz, hist[16], cur[16];
    const int tid = threadIdx.x;
    const int blk = blockIdx.x;

    // ---- per-block dtype detect (node_opt first 2048 u16) ----
    if (tid == 0) { s_big = 0; s_nz = 0; }
    __syncthreads();
    {
        const unsigned short* u = (const unsigned short*)node_opt;
        int big = 0;
        #pragma unroll
        for (int i = 0; i < 4; ++i) {
            const float v = fabsf(bfc(u[tid + i * 512]));
            big |= !(v < 1.0e3f);             // NaN-safe
        }
        if (big) s_big = 1;
        if (node_idx[2 * tid + 1] != 0) s_nz = 1;   // int width probe
    }
    __syncthreads();
    const int isbf = s_big ? 0 : 1;
    const int i64  = s_nz ? 0 : 1;

    if (blk < 400) {
        // ---- rel_proj[r][n] = sum_d rel_embeds[r][d] * W_ih[n][128+d] ----
        const int r = blk;
        if (tid < DR_) relv[tid] = ld(rel_embeds, (size_t)r * DR_ + tid, isbf);
        __syncthreads();
        const int n = tid;                     // 0..511
        float s;
        if (isbf) {
            s = 0.f;
            for (int d = 0; d < DR_; ++d)
                s = fmaf(relv[d], bfc(((const bfraw*)W_ih)[(size_t)n * 256 + 128 + d]), s);
        } else {
            s = dot128((const float*)W_ih + (size_t)n * 256 + 128, relv);
        }
        g_relproj[r * G4_ + n] = s;
    } else if (blk < 656) {
        // ---- W repack: g_Wcat[n][k] = bf16(k<128 ? W_hh[n][k] : W_ih[n][k-128]) ----
        const int idx = (blk - 400) * 512 + tid;   // 0..131071
        const int n = idx >> 8, k = idx & 255;
        const float v = (k < H_) ? ld(W_hh, (size_t)n * H_ + k, isbf)
                                 : ld(W_ih, (size_t)n * 256 + (k - H_), isbf);
        g_Wcat[n * 256 + k] = f2b(v);
    } else {
        // ---- flags + bias + counting sort (len=16 bucket first) ----
        if (tid == 0) { g_isbf16 = isbf; g_isi64 = i64; }
        g_bias[tid] = ld(b_ih, tid, isbf) + ld(b_hh, tid, isbf);
        if (tid < 16) hist[tid] = 0;
        __syncthreads();
        for (int p = tid; p < NPATH; p += 512) {
            const int len = i64 ? path_lens[2 * p] : path_lens[p];
            atomicAdd(&hist[len - 1], 1);
        }
        __syncthreads();
        if (tid == 0) {
            int off = 0;
            for (int b = 15; b >= 0; --b) { cur[b] = off; off += hist[b]; }
        }
        __syncthreads();
        for (int p = tid; p < NPATH; p += 512) {
            const int len = i64 ? path_lens[2 * p] : path_lens[p];
            const int pos = atomicAdd(&cur[len - 1], 1);
            g_perm[pos] = p;
        }
    }
}

// ---------------------------------------------------------------------------
// MFMA LSTM: 256 blocks x 512 threads (8 waves), 32 paths/block, N=512, K=256.
// Wave w owns units u0 = w*16+col for all 4 gates. W fragments resident in
// 128 VGPRs/lane (8 chunks x 4 gates x 16B), loaded once. Per step:
// commit x -> barrier -> 16 ds_read_b128(A) + 64 MFMA -> barrier -> epilogue.
__global__ __launch_bounds__(512, 2) void k_lstm(
    const void* __restrict__ graph_embed,   // [32][4096][128] f32 (or bf16)
    const int*  __restrict__ node_idx,      // [8192][16]
    const int*  __restrict__ rel_idx,       // [8192][16]
    const int*  __restrict__ path_lens)     // [8192]
{
    __shared__ __align__(16) bfraw A[NPB][AST2];    // [path][ h(0:128) | node(128:256) ]
    __shared__ int s_pid[NPB], s_len[NPB];
    __shared__ int s_nid[NPB][L_], s_rid[NPB][L_];

    const int isbf = g_isbf16;
    const int i64  = g_isi64;
    const int tid  = threadIdx.x;

    if (tid < NPB) {
        const int pid = g_perm[blockIdx.x * NPB + tid];
        s_pid[tid] = pid;
        s_len[tid] = i64 ? path_lens[2 * pid] : path_lens[pid];
    }
    __syncthreads();
    {   // indices: 512 threads = 32 paths x 16 steps
        const int m = tid >> 4, t = tid & 15;
        const int idx = s_pid[m] * L_ + t;
        s_nid[m][t] = i64 ? node_idx[2 * idx] : node_idx[idx];
        s_rid[m][t] = i64 ? rel_idx[2 * idx]  : rel_idx[idx];
    }
    {   // zero h region (k<128): 32 rows x 128 bf16
        const int m = tid >> 4, i0 = (tid & 15) * 8;
        *(uint4*)&A[m][i0] = make_uint4(0, 0, 0, 0);
    }
    __syncthreads();

    int maxlen = 0;
    #pragma unroll
    for (int m = 0; m < NPB; ++m) maxlen = max(maxlen, s_len[m]);

    const int w    = tid >> 6;     // wave 0..7
    const int l    = tid & 63;
    const int quad = l >> 4;
    const int col  = l & 15;
    const int u0   = w * 16 + col; // owned unit

    // ---- resident W fragments: wreg[ck][g] = W[g*128+u0][ck*32+quad*8 ..+8] ----
    short8 wreg[8][4];
    float bq4[4];
    #pragma unroll
    for (int g = 0; g < 4; ++g) {
        bq4[g] = g_bias[g * 128 + u0];
        const bfraw* wrow = g_Wcat + (size_t)(g * 128 + u0) * 256 + quad * 8;
        #pragma unroll
        for (int ck = 0; ck < 8; ++ck)
            wreg[ck][g] = *(const short8*)(wrow + ck * 32);
    }

    // x-gather prefetch (thread pm stages 8 node elems at pi0)
    const int pm  = tid >> 4;
    const int pi0 = (tid & 15) * 8;
    const size_t gbase = (size_t)(s_pid[pm] >> 8) * (size_t)(N_ * DR_);
    uint4 pn0, pn1;
    {
        const int nid = s_nid[pm][0];
        if (isbf) {
            pn0 = *(const uint4*)((const bfraw*)graph_embed + gbase + (size_t)nid * DR_ + pi0);
        } else {
            const float* gp = (const float*)graph_embed + gbase + (size_t)nid * DR_ + pi0;
            pn0 = *(const uint4*)gp; pn1 = *(const uint4*)(gp + 4);
        }
    }

    float c[2][4];
    #pragma unroll
    for (int mt = 0; mt < 2; ++mt)
        #pragma unroll
        for (int r = 0; r < 4; ++r) c[mt][r] = 0.f;

    for (int t = 0; t < maxlen; ++t) {
        // ---- commit prefetched node x(t) into A (masked) ----
        {
            uint4 npk = make_uint4(0, 0, 0, 0);
            if (t < s_len[pm]) {
                if (isbf) npk = pn0;
                else {
                    const float* a = (const float*)&pn0;
                    const float* b = (const float*)&pn1;
                    npk = make_uint4(pk2(a[0],a[1]), pk2(a[2],a[3]),
                                     pk2(b[0],b[1]), pk2(b[2],b[3]));
                }
            }
            *(uint4*)&A[pm][128 + pi0] = npk;
        }
        __syncthreads();                 // x(t) + h(t-1) visible

        // ---- issue x prefetch for t+1 (block-uniform branch) ----
        if (t + 1 < maxlen) {
            const int nid = s_nid[pm][t + 1];
            if (isbf) {
                pn0 = *(const uint4*)((const bfraw*)graph_embed + gbase + (size_t)nid * DR_ + pi0);
            } else {
                const float* gp = (const float*)graph_embed + gbase + (size_t)nid * DR_ + pi0;
                pn0 = *(const uint4*)gp; pn1 = *(const uint4*)(gp + 4);
            }
        }

        // ---- MFMA K-loop: A from LDS, W from registers ----
        f32x4 acc[2][4];
        #pragma unroll
        for (int mt = 0; mt < 2; ++mt)
            #pragma unroll
            for (int g = 0; g < 4; ++g) {
                const float b = bq4[g];
                acc[mt][g][0] = b; acc[mt][g][1] = b;
                acc[mt][g][2] = b; acc[mt][g][3] = b;
            }
        #pragma unroll
        for (int ck = 0; ck < 8; ++ck) {
            const short8 a0 = *(const short8*)&A[col][ck * 32 + quad * 8];
            const short8 a1 = *(const short8*)&A[16 + col][ck * 32 + quad * 8];
            #pragma unroll
            for (int g = 0; g < 4; ++g) {
                acc[0][g] = __builtin_amdgcn_mfma_f32_16x16x32_bf16(a0, wreg[ck][g], acc[0][g], 0, 0, 0);
                acc[1][g] = __builtin_amdgcn_mfma_f32_16x16x32_bf16(a1, wreg[ck][g], acc[1][g], 0, 0, 0);
            }
        }

        // ---- rel_proj gathers (issued while MFMAs drain) ----
        float rl[2][4][4];
        #pragma unroll
        for (int mt = 0; mt < 2; ++mt)
            #pragma unroll
            for (int r = 0; r < 4; ++r) {
                const int m = mt * 16 + quad * 4 + r;
                const float* rp = g_relproj + (size_t)s_rid[m][t] * G4_ + u0;
                #pragma unroll
                for (int g = 0; g < 4; ++g) rl[mt][g][r] = rp[g * 128];
            }
        __syncthreads();                 // all A reads done before h overwrite

        // ---- gates + cell update + h write + snapshot ----
        #pragma unroll
        for (int mt = 0; mt < 2; ++mt)
            #pragma unroll
            for (int r = 0; r < 4; ++r) {
                const int m = mt * 16 + quad * 4 + r;
                const float relm = (t < s_len[m] - 1) ? 1.0f : 0.0f;
                const float ig = sigf(acc[mt][0][r] + relm * rl[mt][0][r]);
                const float fg = sigf(acc[mt][1][r] + relm * rl[mt][1][r]);
                const float gg = tanhfast(acc[mt][2][r] + relm * rl[mt][2][r]);
                const float og = sigf(acc[mt][3][r] + relm * rl[mt][3][r]);
                const float cc = fg * c[mt][r] + ig * gg;
                c[mt][r] = cc;
                const float h = og * tanhfast(cc);
                A[m][u0] = f2b(h);
                if (t == s_len[m] - 1)
                    g_last[(size_t)s_pid[m] * H_ + u0] = h;
            }
        // h-writes (k<128) and next x-commit (k>=128) are disjoint; the next
        // top-of-step barrier orders them vs A reads.
    }
}

// ---------------------------------------------------------------------------
// Attention epilogue, one block per batch element.
__global__ __launch_bounds__(256) void k_attn(
    const void* __restrict__ node_opt,    // [32][128]
    const void* __restrict__ in_proj_w,   // [384][128]
    const void* __restrict__ in_proj_b,   // [384]
    const void* __restrict__ out_proj_w,  // [128][128]
    const void* __restrict__ out_proj_b,  // [128]
    float* __restrict__ out)              // [32][128] f32
{
    const int isbf = g_isbf16;
    const int b = blockIdx.x, tid = threadIdx.x;
    __shared__ __align__(16) float s_no[128], q[128], qk[128], sv2[2][128], ctx[128];
    __shared__ float logits[256];
    __shared__ float red[12];

    if (tid < 128) s_no[tid] = ld(node_opt, b * 128 + tid, isbf);
    __syncthreads();
    if (tid < 128) {
        float s;
        if (isbf) {
            s = 0.f;
            for (int j = 0; j < 128; ++j)
                s = fmaf(s_no[j], ld(in_proj_w, (size_t)tid * 128 + j, 1), s);
        } else {
            s = dot128((const float*)in_proj_w + (size_t)tid * 128, s_no);
        }
        q[tid] = s + ld(in_proj_b, tid, isbf);
    }
    __syncthreads();
    if (tid < 128) {   // qk[u] = sum_j q[j] * Wk[j][u]
        float s = 0.f;
        for (int j = 0; j < 128; ++j)
            s = fmaf(q[j], ld(in_proj_w, (size_t)(128 + j) * 128 + tid, isbf), s);
        qk[tid] = s;
    } else if (tid == 128) {
        float s = 0.f;
        for (int j = 0; j < 128; ++j)
            s = fmaf(q[j], ld(in_proj_b, 128 + j, isbf), s);
        red[10] = s;   // q . bk
    }
    __syncthreads();
    {   // logit for path p = tid
        const float* lp = g_last + ((size_t)b * 256 + tid) * H_;
        const float s = dot128(lp, qk);
        logits[tid] = (s + red[10]) * 0.08838834764831845f;  // 1/sqrt(128)
    }
    __syncthreads();
    float v = logits[tid];
    #pragma unroll
    for (int off = 32; off > 0; off >>= 1) v = fmaxf(v, __shfl_xor(v, off, 64));
    if ((tid & 63) == 0) red[tid >> 6] = v;
    __syncthreads();
    if (tid == 0) red[8] = fmaxf(fmaxf(red[0], red[1]), fmaxf(red[2], red[3]));
    __syncthreads();
    const float e = __expf(logits[tid] - red[8]);
    float sum = e;
    #pragma unroll
    for (int off = 32; off > 0; off >>= 1) sum += __shfl_xor(sum, off, 64);
    if ((tid & 63) == 0) red[4 + (tid >> 6)] = sum;
    __syncthreads();
    if (tid == 0) red[9] = red[4] + red[5] + red[6] + red[7];
    __syncthreads();
    logits[tid] = e / red[9];
    __syncthreads();
    {   // sv[u] = sum_p attn[p] * last[b,p,u]
        const int u = tid & 127, half = tid >> 7;
        float s = 0.f;
        const float* lb = g_last + ((size_t)b * 256 + half * 128) * H_ + u;
        for (int p = 0; p < 128; ++p)
            s = fmaf(logits[half * 128 + p], lb[(size_t)p * H_], s);
        sv2[half][u] = s;
    }
    __syncthreads();
    if (tid < 128) q[tid] = sv2[0][tid] + sv2[1][tid];   // reuse q[] as sv
    __syncthreads();
    if (tid < 128) {
        float s;
        if (isbf) {
            s = 0.f;
            for (int u = 0; u < 128; ++u)
                s = fmaf(q[u], ld(in_proj_w, (size_t)(256 + tid) * 128 + u, 1), s);
        } else {
            s = dot128((const float*)in_proj_w + (size_t)(256 + tid) * 128, q);
        }
        ctx[tid] = s + ld(in_proj_b, 256 + tid, isbf);
    }
    __syncthreads();
    if (tid < 128) {
        float s;
        if (isbf) {
            s = 0.f;
            for (int d = 0; d < 128; ++d)
                s = fmaf(ctx[d], ld(out_proj_w, (size_t)tid * 128 + d, 1), s);
        } else {
            s = dot128((const float*)out_proj_w + (size_t)tid * 128, ctx);
        }
        out[b * 128 + tid] = s + ld(out_proj_b, tid, isbf);
    }
}

// ---------------------------------------------------------------------------
extern "C" void kernel_launch(void* const* d_in, const int* in_sizes, int n_in,
                              void* d_out, int out_size, void* d_ws, size_t ws_size,
                              hipStream_t stream)
{
    const void* graph_embed = d_in[0];
    const void* node_opt    = d_in[1];
    const void* rel_embeds  = d_in[2];
    const void* W_ih        = d_in[3];
    const void* W_hh        = d_in[4];
    const void* b_ih        = d_in[5];
    const void* b_hh        = d_in[6];
    const void* in_proj_w   = d_in[7];
    const void* in_proj_b   = d_in[8];
    const void* out_proj_w  = d_in[9];
    const void* out_proj_b  = d_in[10];
    const int* node_idx  = (const int*)d_in[11];
    const int* rel_idx   = (const int*)d_in[12];
    const int* path_lens = (const int*)d_in[13];
    (void)d_ws; (void)ws_size; (void)in_sizes; (void)n_in; (void)out_size;

    hipLaunchKernelGGL(k_prep, dim3(657), dim3(512), 0, stream,
                       node_opt, node_idx, rel_embeds, W_ih, W_hh, b_ih, b_hh,
                       path_lens);
    hipLaunchKernelGGL(k_lstm, dim3(NPATH / NPB), dim3(512), 0, stream,
                       graph_embed, node_idx, rel_idx, path_lens);
    hipLaunchKernelGGL(k_attn, dim3(B_), dim3(256), 0, stream,
                       node_opt, in_proj_w, in_proj_b, out_proj_w, out_proj_b,
                       (float*)d_out);
}